// Round 5
// baseline (54.115 us; speedup 1.0000x reference)
//
#include <hip/hip_runtime.h>

#define TPB 256
#define H 64
#define W 64
#define OYB 16

// t1: W-upsampled rows, t1r = 0..23 <-> input row (oy0-4+t1r)
#define NT1 24
#define T1_STRIDE 132     // ==4 mod 32: b128 write / b64 col-read at bank minimum
#define T1_FLOATS (NT1 * T1_STRIDE)    // 3168 floats
#define LDS_FLOATS T1_FLOATS           // 12672 B -> wave-capped 8 blocks/CU (100% occupancy)

typedef float v2f __attribute__((ext_vector_type(2)));

// v_pk_*_f32 (CDNA2+ packed fp32). op_sel[i] = src-i half for LOW result,
// op_sel_hi[i] = src-i half for HIGH result. Plain = [0,..]/[1,..].
#define PKF_ACC_A0(acc,a,b) asm("v_pk_fma_f32 %0, %1, %2, %0 op_sel:[0,0,0] op_sel_hi:[0,1,1]" : "+v"(acc) : "v"(a), "v"(b))  // src0 bcast lo
#define PKF_ACC_A1(acc,a,b) asm("v_pk_fma_f32 %0, %1, %2, %0 op_sel:[1,0,0] op_sel_hi:[1,1,1]" : "+v"(acc) : "v"(a), "v"(b))  // src0 bcast hi
#define PKF_ACC_B0(acc,a,b) asm("v_pk_fma_f32 %0, %1, %2, %0 op_sel:[0,0,0] op_sel_hi:[1,0,1]" : "+v"(acc) : "v"(a), "v"(b))  // src1 bcast lo
#define PKF_ACC_B1(acc,a,b) asm("v_pk_fma_f32 %0, %1, %2, %0 op_sel:[0,1,0] op_sel_hi:[1,1,1]" : "+v"(acc) : "v"(a), "v"(b))  // src1 bcast hi
#define PKF_NEW_B0(d,a,b,c) asm("v_pk_fma_f32 %0, %1, %2, %3 op_sel:[0,0,0] op_sel_hi:[1,0,1]" : "=v"(d) : "v"(a), "v"(b), "v"(c))
#define PKF_NEW_B1(d,a,b,c) asm("v_pk_fma_f32 %0, %1, %2, %3 op_sel:[0,1,0] op_sel_hi:[1,1,1]" : "=v"(d) : "v"(a), "v"(b), "v"(c))
#define PKM_A0(d,a,b)       asm("v_pk_mul_f32 %0, %1, %2 op_sel:[0,0] op_sel_hi:[0,1]" : "=v"(d) : "v"(a), "v"(b))            // src0 bcast lo
#define PKM_A1(d,a,b)       asm("v_pk_mul_f32 %0, %1, %2 op_sel:[1,0] op_sel_hi:[1,1]" : "=v"(d) : "v"(a), "v"(b))            // src0 bcast hi
#define PKM_B0(d,a,b)       asm("v_pk_mul_f32 %0, %1, %2 op_sel:[0,0] op_sel_hi:[1,0]" : "=v"(d) : "v"(a), "v"(b))            // src1 bcast lo

__global__ __launch_bounds__(TPB, 8)
void afa_fused(const float* __restrict__ in, const float* __restrict__ bias,
               const float* __restrict__ upf, const float* __restrict__ dnf,
               float* __restrict__ out)
{
    __shared__ __align__(16) float s_t1[LDS_FLOATS];   // [24][132]

    const int tid = threadIdx.x;
    const int blk = blockIdx.x;
    const int plane = blk >> 2;
    const int oy0 = (blk & 3) * OYB;

    // ---- tap setup.
    // gp[k] = {g[9-2k], g[10-2k]}: W-up/H-up phase-pair taps (g = 2*filt; filt[0]=filt[11]=0).
    // fh[j] = {sqrt2*f[2j+1], sqrt2*f[2j+2]}: H-down taps with the LReLU sqrt2 folded in.
    v2f gp[5], fh[5];
#pragma unroll
    for (int k = 0; k < 5; ++k) {
        gp[k] = (v2f){2.0f * upf[9 - 2*k], 2.0f * upf[10 - 2*k]};
        fh[k] = (v2f){1.41421356237309515f * dnf[2*k + 1], 1.41421356237309515f * dnf[2*k + 2]};
    }
    // W-down packed tap pairs for the cross-lane partials:
    // R_{-2},R_{-1} use {fd2,fd4}/{fd1,fd3}; R_1,R_2 use {fd8,fd10}/{fd7,fd9}; center fd6,fd5.
    const v2f cdA = (v2f){dnf[2], dnf[4]};
    const v2f cdB = (v2f){dnf[1], dnf[3]};
    const v2f cdC = (v2f){dnf[8], dnf[10]};
    const v2f cdD = (v2f){dnf[7], dnf[9]};
    const float fd6 = dnf[6], fd5 = dnf[5];
    const float bv = bias[plane & 511];
    const v2f b2  = (v2f){bv, bv};
    const v2f cst = (v2f){0.6f, 0.4f};                  // lrelu: 0.6x + 0.4|x| (sqrt2 folded into fh)
    const v2f z2  = (v2f){0.f, 0.f};

    // ---- edge stripes: zero the 4 t1 rows whose input row is outside [0,64)
    if (oy0 == 0 || oy0 == 48) {
        const int rb0 = (oy0 == 0) ? 0 : 20;
        for (int w = tid; w < 4 * T1_STRIDE; w += TPB)
            s_t1[rb0 * T1_STRIDE + w] = 0.f;
    }

    // ---- A: global load + horizontal (W) x2 upsample -> t1 (bias commutes past linear convs).
    if (tid < NT1 * 8) {
        const int ri = tid >> 3;
        const int r = oy0 - 4 + ri;
        if ((unsigned)r < (unsigned)H) {
            const int cb = tid & 7;
            const float4* p4 = (const float4*)(in + (size_t)plane * (H * W) + r * W);
            const float4 z4 = make_float4(0.f, 0.f, 0.f, 0.f);
            const float4 q0 = (cb == 0) ? z4 : p4[2 * cb - 1];
            const float4 q1 = p4[2 * cb];
            const float4 q2 = p4[2 * cb + 1];
            const float4 q3 = (cb == 7) ? z4 : p4[2 * cb + 2];
            v2f wr2[6];                      // window x[8cb-2 .. 8cb+9] as 6 pairs
            wr2[0] = (v2f){q0.z, q0.w};
            wr2[1] = (v2f){q1.x, q1.y};  wr2[2] = (v2f){q1.z, q1.w};
            wr2[3] = (v2f){q2.x, q2.y};  wr2[4] = (v2f){q2.z, q2.w};
            wr2[5] = (v2f){q3.x, q3.y};
            v2f po[8];
#pragma unroll
            for (int q = 0; q < 8; ++q) {
                if (q & 1) { PKM_A1(po[q], wr2[q >> 1], gp[0]); }
                else       { PKM_A0(po[q], wr2[q >> 1], gp[0]); }
#pragma unroll
                for (int k = 1; k < 5; ++k) {
                    if ((q + k) & 1) { PKF_ACC_A1(po[q], wr2[(q + k) >> 1], gp[k]); }
                    else             { PKF_ACC_A0(po[q], wr2[(q + k) >> 1], gp[k]); }
                }
            }
            float* dst = s_t1 + ri * T1_STRIDE + 16 * cb;
#pragma unroll
            for (int k = 0; k < 4; ++k)
                *(float4*)(dst + 4 * k) = make_float4(po[2*k][0], po[2*k][1], po[2*k+1][0], po[2*k+1][1]);
        }
    }
    __syncthreads();

    // ---- fusedV: per column-pair, H-up + bias + LReLU + H-down in registers,
    //      then W-down via cross-lane partials (wave = one t2 row) + store.
    {
        const int c = tid & 63;                   // lane = col-pair (cols 2c, 2c+1)
        const int q4 = tid >> 6;                  // wave-uniform row quarter
        const bool mlo = (oy0 == 0)  && (q4 == 0);
        const bool mhi = (oy0 == 48) && (q4 == 3);
        v2f cc[12];
#pragma unroll
        for (int t = 0; t < 12; ++t)
            cc[t] = *(const v2f*)(s_t1 + (4 * q4 + t) * T1_STRIDE + 2 * c);
        v2f acc[4] = {z2, z2, z2, z2};
#pragma unroll
        for (int t = 0; t < 8; ++t) {
            v2f ta, tb;
            PKF_NEW_B0(ta, cc[t], gp[0], b2);
            PKF_NEW_B1(tb, cc[t], gp[0], b2);
#pragma unroll
            for (int k = 1; k < 5; ++k) {
                PKF_ACC_B0(ta, cc[t + k], gp[k]);
                PKF_ACC_B1(tb, cc[t + k], gp[k]);
            }
            if (mlo && t < 2)  { ta = z2; tb = z2; }
            if (mhi && t >= 6) { ta = z2; tb = z2; }
            v2f ra, aa, rb, ab;
            PKM_B0(ra, ta, cst);
            aa.x = __builtin_fabsf(ta.x); aa.y = __builtin_fabsf(ta.y);
            PKF_ACC_B1(ra, aa, cst);
            PKM_B0(rb, tb, cst);
            ab.x = __builtin_fabsf(tb.x); ab.y = __builtin_fabsf(tb.y);
            PKF_ACC_B1(rb, ab, cst);
#pragma unroll
            for (int p = 0; p < 4; ++p) {
                if (p >= t - 4 && p <= t) {
                    PKF_ACC_B1(acc[p], ra, fh[4 - (t - p)]);
                    PKF_ACC_B0(acc[p], rb, fh[4 - (t - p)]);
                }
            }
        }

        // W-down: out[ox=c] = R0(c) + sum_{e in {-2,-1,1,2}} R_e(lane c-e), zero outside [0,64).
        const bool vp2 = (c <= 61), vp1 = (c <= 62), vm1 = (c >= 1), vm2 = (c >= 2);
        float* po = out + (size_t)plane * (H * W) + (oy0 + 4 * q4) * W + c;
#pragma unroll
        for (int p = 0; p < 4; ++p) {
            const v2f A = acc[p];
            v2f tlo, thi;
            // tlo = {R_-2, R_-1} = {A.x*fd2 + A.y*fd1, A.x*fd4 + A.y*fd3}
            PKM_A0(tlo, A, cdA);
            PKF_ACC_A1(tlo, A, cdB);
            // thi = {R_1, R_2} = {A.x*fd8 + A.y*fd7, A.x*fd10 + A.y*fd9}
            PKM_A0(thi, A, cdC);
            PKF_ACC_A1(thi, A, cdD);
            float r = A.x * fd6 + A.y * fd5;      // R_0
            const float gm2 = __shfl(tlo.x, c + 2);   // R_-2 from lane c+2
            const float gm1 = __shfl(tlo.y, c + 1);   // R_-1 from lane c+1
            const float gp1 = __shfl(thi.x, c - 1);   // R_1  from lane c-1
            const float gp2 = __shfl(thi.y, c - 2);   // R_2  from lane c-2
            r += vp2 ? gm2 : 0.f;
            r += vp1 ? gm1 : 0.f;
            r += vm1 ? gp1 : 0.f;
            r += vm2 ? gp2 : 0.f;
            po[p * W] = r;
        }
    }
}

extern "C" void kernel_launch(void* const* d_in, const int* in_sizes, int n_in,
                              void* d_out, int out_size, void* d_ws, size_t ws_size,
                              hipStream_t stream) {
    const float* in  = (const float*)d_in[0];
    const float* bv  = (const float*)d_in[1];
    const float* upf = (const float*)d_in[2];
    const float* dnf = (const float*)d_in[3];
    float* out = (float*)d_out;
    const int planes = 8 * 512;
    afa_fused<<<planes * 4, TPB, 0, stream>>>(in, bv, upf, dnf, out);
}

// Round 6
// 54.049 us; speedup vs baseline: 1.0012x; 1.0012x over previous
//
#include <hip/hip_runtime.h>

#define TPB 256
#define H 64
#define W 64
#define OYB 16

// t1: W-upsampled rows, t1r = 0..23 <-> input row (oy0-4+t1r)
#define NT1 24
#define T1_STRIDE 132     // ==4 mod 32: b128 write / b64 col-read at bank minimum
#define T1_FLOATS (NT1 * T1_STRIDE)    // 3168 floats = 12672 B
// t2: H-downsampled rows (16 x 128 + 4-col halos) -- ALIASES t1 (acc in regs across barrier)
#define T2_STRIDE 140
#define T2_OFF 4
#define LDS_FLOATS T1_FLOATS           // 12672 B -> 8 blocks/CU (thread-cap), 100% occupancy

typedef float v2f __attribute__((ext_vector_type(2)));

// v_pk_*_f32 (CDNA2+ packed fp32). op_sel[i] = src-i half for LOW result,
// op_sel_hi[i] = src-i half for HIGH result. Plain = [0,..]/[1,..].
#define PKF_ACC_A0(acc,a,b) asm("v_pk_fma_f32 %0, %1, %2, %0 op_sel:[0,0,0] op_sel_hi:[0,1,1]" : "+v"(acc) : "v"(a), "v"(b))  // src0 bcast lo
#define PKF_ACC_A1(acc,a,b) asm("v_pk_fma_f32 %0, %1, %2, %0 op_sel:[1,0,0] op_sel_hi:[1,1,1]" : "+v"(acc) : "v"(a), "v"(b))  // src0 bcast hi
#define PKF_ACC_B0(acc,a,b) asm("v_pk_fma_f32 %0, %1, %2, %0 op_sel:[0,0,0] op_sel_hi:[1,0,1]" : "+v"(acc) : "v"(a), "v"(b))  // src1 bcast lo
#define PKF_ACC_B1(acc,a,b) asm("v_pk_fma_f32 %0, %1, %2, %0 op_sel:[0,1,0] op_sel_hi:[1,1,1]" : "+v"(acc) : "v"(a), "v"(b))  // src1 bcast hi
#define PKF_NEW_B0(d,a,b,c) asm("v_pk_fma_f32 %0, %1, %2, %3 op_sel:[0,0,0] op_sel_hi:[1,0,1]" : "=v"(d) : "v"(a), "v"(b), "v"(c))
#define PKF_NEW_B1(d,a,b,c) asm("v_pk_fma_f32 %0, %1, %2, %3 op_sel:[0,1,0] op_sel_hi:[1,1,1]" : "=v"(d) : "v"(a), "v"(b), "v"(c))
#define PKM_A0(d,a,b)       asm("v_pk_mul_f32 %0, %1, %2 op_sel:[0,0] op_sel_hi:[0,1]" : "=v"(d) : "v"(a), "v"(b))            // src0 bcast lo
#define PKM_A1(d,a,b)       asm("v_pk_mul_f32 %0, %1, %2 op_sel:[1,0] op_sel_hi:[1,1]" : "=v"(d) : "v"(a), "v"(b))            // src0 bcast hi
#define PKM(d,a,b)          asm("v_pk_mul_f32 %0, %1, %2 op_sel:[0,0] op_sel_hi:[1,1]" : "=v"(d) : "v"(a), "v"(b))            // plain

__global__ __launch_bounds__(TPB, 8)
void afa_fused(const float* __restrict__ in, const float* __restrict__ bias,
               const float* __restrict__ upf, const float* __restrict__ dnf,
               float* __restrict__ out)
{
    __shared__ __align__(16) float lds[LDS_FLOATS];
    float* const s_t1 = lds;     // [24][132]
    float* const s_t2 = lds;     // [16][140], aliases t1 after fusedV reads complete

    const int tid = threadIdx.x;
    const int blk = blockIdx.x;
    const int plane = blk >> 2;
    const int oy0 = (blk & 3) * OYB;

    // ---- tap setup.
    // gp[k] = {g[9-2k], g[10-2k]}: W-up/H-up phase-pair taps (g = 2*filt; filt[0]=filt[11]=0).
    // fh[j] = {sqrt2*f[2j+1], sqrt2*f[2j+2]}: H-down taps with the LReLU sqrt2 folded in.
    v2f gp[5], fh[5];
#pragma unroll
    for (int k = 0; k < 5; ++k) {
        gp[k] = (v2f){2.0f * upf[9 - 2*k], 2.0f * upf[10 - 2*k]};
        fh[k] = (v2f){1.41421356237309515f * dnf[2*k + 1], 1.41421356237309515f * dnf[2*k + 2]};
    }
    float fd[11];
#pragma unroll
    for (int k = 1; k <= 10; ++k) fd[k] = dnf[k];       // W-down taps (unscaled)
    const float bv = bias[plane & 511];
    const v2f b2  = (v2f){bv, bv};
    const v2f cm2 = (v2f){0.2f, 0.2f};                  // lrelu slope (sqrt2 folded into fh)
    const v2f z2  = (v2f){0.f, 0.f};

    // ---- edge stripes: zero the 4 t1 rows whose input row is outside [0,64)
    if (oy0 == 0 || oy0 == 48) {
        const int rb0 = (oy0 == 0) ? 0 : 20;
        for (int w = tid; w < 4 * T1_STRIDE; w += TPB)
            s_t1[rb0 * T1_STRIDE + w] = 0.f;
    }

    // ---- A: global load + horizontal (W) x2 upsample -> t1 (bias commutes past linear convs).
    if (tid < NT1 * 8) {
        const int ri = tid >> 3;
        const int r = oy0 - 4 + ri;
        if ((unsigned)r < (unsigned)H) {
            const int cb = tid & 7;
            const float4* p4 = (const float4*)(in + (size_t)plane * (H * W) + r * W);
            const float4 z4 = make_float4(0.f, 0.f, 0.f, 0.f);
            const float4 q0 = (cb == 0) ? z4 : p4[2 * cb - 1];
            const float4 q1 = p4[2 * cb];
            const float4 q2 = p4[2 * cb + 1];
            const float4 q3 = (cb == 7) ? z4 : p4[2 * cb + 2];
            v2f wr2[6];                      // window x[8cb-2 .. 8cb+9] as 6 pairs
            wr2[0] = (v2f){q0.z, q0.w};
            wr2[1] = (v2f){q1.x, q1.y};  wr2[2] = (v2f){q1.z, q1.w};
            wr2[3] = (v2f){q2.x, q2.y};  wr2[4] = (v2f){q2.z, q2.w};
            wr2[5] = (v2f){q3.x, q3.y};
            v2f po[8];
#pragma unroll
            for (int q = 0; q < 8; ++q) {
                if (q & 1) { PKM_A1(po[q], wr2[q >> 1], gp[0]); }
                else       { PKM_A0(po[q], wr2[q >> 1], gp[0]); }
#pragma unroll
                for (int k = 1; k < 5; ++k) {
                    if ((q + k) & 1) { PKF_ACC_A1(po[q], wr2[(q + k) >> 1], gp[k]); }
                    else             { PKF_ACC_A0(po[q], wr2[(q + k) >> 1], gp[k]); }
                }
            }
            float* dst = s_t1 + ri * T1_STRIDE + 16 * cb;
#pragma unroll
            for (int k = 0; k < 4; ++k)
                *(float4*)(dst + 4 * k) = make_float4(po[2*k][0], po[2*k][1], po[2*k+1][0], po[2*k+1][1]);
        }
    }
    __syncthreads();

    // ---- fusedV: per column-pair, H-up + bias + LReLU + H-down entirely in registers.
    // thread: cols (2c, 2c+1), quarter q4 -> t2 rows 4q4..4q4+3; reads t1 rows 4q4..4q4+11.
    const int c = tid & 63;
    const int q4 = tid >> 6;                  // wave-uniform
    v2f acc[4] = {z2, z2, z2, z2};
    {
        const bool mlo = (oy0 == 0)  && (q4 == 0);
        const bool mhi = (oy0 == 48) && (q4 == 3);
        v2f cc[12];
#pragma unroll
        for (int t = 0; t < 12; ++t)
            cc[t] = *(const v2f*)(s_t1 + (4 * q4 + t) * T1_STRIDE + 2 * c);
#pragma unroll
        for (int t = 0; t < 8; ++t) {
            // ir rows s=2t (odd jj, taps gp[k].x) and s=2t+1 (even jj, taps gp[k].y), window cc[t..t+4]
            v2f ta, tb;
            PKF_NEW_B0(ta, cc[t], gp[0], b2);
            PKF_NEW_B1(tb, cc[t], gp[0], b2);
#pragma unroll
            for (int k = 1; k < 5; ++k) {
                PKF_ACC_B0(ta, cc[t + k], gp[k]);
                PKF_ACC_B1(tb, cc[t + k], gp[k]);
            }
            if (mlo && t < 2)  { ta = z2; tb = z2; }    // zero-pad rows outside the 128-row frame
            if (mhi && t >= 6) { ta = z2; tb = z2; }
            // lrelu (unscaled): r = max(x, 0.2x)
            v2f ra, rb;
            PKM(ra, ta, cm2);
            ra.x = __builtin_fmaxf(ta.x, ra.x);
            ra.y = __builtin_fmaxf(ta.y, ra.y);
            PKM(rb, tb, cm2);
            rb.x = __builtin_fmaxf(tb.x, rb.x);
            rb.y = __builtin_fmaxf(tb.y, rb.y);
            // H-down accumulate: even s -> fh[4-(t-p)].y, odd s -> .x
#pragma unroll
            for (int p = 0; p < 4; ++p) {
                if (p >= t - 4 && p <= t) {
                    PKF_ACC_B1(acc[p], ra, fh[4 - (t - p)]);
                    PKF_ACC_B0(acc[p], rb, fh[4 - (t - p)]);
                }
            }
        }
    }
    __syncthreads();   // all t1 reads done; t2 may now overwrite the same LDS

    // ---- store acc -> t2 (aliased) + halo cols
#pragma unroll
    for (int p = 0; p < 4; ++p)
        *(v2f*)(s_t2 + (4 * q4 + p) * T2_STRIDE + T2_OFF + 2 * c) = acc[p];
    if (tid < 128) {
        const int rw = tid >> 3, cz = tid & 7;
        const int col = (cz < 4) ? cz : (128 + cz);
        s_t2[rw * T2_STRIDE + col] = 0.f;
    }
    __syncthreads();

    // ---- Wdown: horizontal (W) /2 downsample of t2 -> global (coalesced float4).
    {
        const int oy = tid >> 4, oxb = tid & 15;
        const float* base = s_t2 + oy * T2_STRIDE + 8 * oxb;   // word T2_OFF + (8oxb-4)
        float wv[16];
#pragma unroll
        for (int t = 0; t < 4; ++t) {
            const float4 v = *(const float4*)(base + 4 * t);
            wv[4*t] = v.x; wv[4*t+1] = v.y; wv[4*t+2] = v.z; wv[4*t+3] = v.w;
        }
        float o2[4];
#pragma unroll
        for (int p = 0; p < 4; ++p) {
            float acc2 = 0.f;
#pragma unroll
            for (int k = 0; k < 10; ++k)
                acc2 += wv[2*p + k] * fd[10 - k];
            o2[p] = acc2;
        }
        float* po = out + (size_t)plane * (H * W) + (oy0 + oy) * W + 4 * oxb;
        *(float4*)po = make_float4(o2[0], o2[1], o2[2], o2[3]);
    }
}

extern "C" void kernel_launch(void* const* d_in, const int* in_sizes, int n_in,
                              void* d_out, int out_size, void* d_ws, size_t ws_size,
                              hipStream_t stream) {
    const float* in  = (const float*)d_in[0];
    const float* bv  = (const float*)d_in[1];
    const float* upf = (const float*)d_in[2];
    const float* dnf = (const float*)d_in[3];
    float* out = (float*)d_out;
    const int planes = 8 * 512;
    afa_fused<<<planes * 4, TPB, 0, stream>>>(in, bv, upf, dnf, out);
}

// Round 7
// 42.191 us; speedup vs baseline: 1.2826x; 1.2811x over previous
//
#include <hip/hip_runtime.h>

#define TPB 512
#define H 64
#define W 64

// t1: W-upsampled rows, T = 0..71 <-> input row r = T-4 (rows 0..3 / 68..71 are zero pad)
#define NT1 72
#define T1_STRIDE 132     // ==4 mod 32: b128 write / b64 col-read at bank minimum
#define T1_FLOATS (NT1 * T1_STRIDE)    // 9504 floats = 38016 B
// t2: H-downsampled rows (64 x 128 + 4-col halos), ALIASES t1 (acc in regs across barrier)
#define T2_STRIDE 140
#define T2_OFF 4
#define LDS_FLOATS T1_FLOATS           // 38016 B -> 4 blocks/CU by LDS

typedef float v2f __attribute__((ext_vector_type(2)));

__global__ __launch_bounds__(TPB, 6)
void afa_fused(const float* __restrict__ in, const float* __restrict__ bias,
               const float* __restrict__ upf, const float* __restrict__ dnf,
               float* __restrict__ out)
{
    __shared__ __align__(16) float lds[LDS_FLOATS];
    float* const s_t1 = lds;    // [72][132]
    float* const s_t2 = lds;    // [64][140], aliases t1 after fusedV reads complete

    const int tid = threadIdx.x;
    const int plane = blockIdx.x;            // 4096 planes, one per block

    // ---- taps (uniform -> SGPRs). filt[0] = filt[11] = 0 structurally.
    // gA[k] = 2*filt[9-2k] (ir row s=2t), gB[k] = 2*filt[10-2k] (s=2t+1)
    // fhx[m] = sqrt2*f[2m+1], fhy[m] = sqrt2*f[2m+2]  (H-down, lrelu sqrt2 folded in)
    float gA[5], gB[5], fhx[5], fhy[5], fd[11];
#pragma unroll
    for (int k = 0; k < 5; ++k) {
        gA[k]  = 2.0f * upf[9 - 2*k];
        gB[k]  = 2.0f * upf[10 - 2*k];
        fhx[k] = 1.41421356237309515f * dnf[2*k + 1];
        fhy[k] = 1.41421356237309515f * dnf[2*k + 2];
    }
#pragma unroll
    for (int k = 1; k <= 10; ++k) fd[k] = dnf[k];   // W-down taps (unscaled)
    const float bv = bias[plane & 511];

    // ---- zero t1 pad rows 0..3 and 68..71 (4*132 = 528 words each side)
    if (tid < 264) {
        *(float2*)(s_t1 + 2 * tid) = make_float2(0.f, 0.f);
        *(float2*)(s_t1 + 68 * T1_STRIDE + 2 * tid) = make_float2(0.f, 0.f);
    }

    // ---- A: global load + horizontal (W) x2 upsample -> t1. 512 units = (r 0..63, cb 0..7).
    {
        const int r  = tid >> 3;
        const int cb = tid & 7;
        const float4* p4 = (const float4*)(in + (size_t)plane * (H * W) + r * W);
        float4 q0 = p4[cb == 0 ? 0 : 2 * cb - 1];     // clamped (no OOB), zeroed below
        const float4 q1 = p4[2 * cb];
        const float4 q2 = p4[2 * cb + 1];
        float4 q3 = p4[cb == 7 ? 15 : 2 * cb + 2];
        if (cb == 0) q0 = make_float4(0.f, 0.f, 0.f, 0.f);
        if (cb == 7) q3 = make_float4(0.f, 0.f, 0.f, 0.f);
        float xr[12] = {q0.z, q0.w, q1.x, q1.y, q1.z, q1.w,
                        q2.x, q2.y, q2.z, q2.w, q3.x, q3.y};   // x[8cb-2 .. 8cb+9]
        float o[16];
#pragma unroll
        for (int q = 0; q < 8; ++q) {
            float e = xr[q] * gA[0];
            float d = xr[q] * gB[0];
#pragma unroll
            for (int k = 1; k < 5; ++k) {
                e = fmaf(xr[q + k], gA[k], e);
                d = fmaf(xr[q + k], gB[k], d);
            }
            o[2*q] = e; o[2*q+1] = d;
        }
        float* dst = s_t1 + (r + 4) * T1_STRIDE + 16 * cb;
#pragma unroll
        for (int k = 0; k < 4; ++k)
            *(float4*)(dst + 4 * k) = make_float4(o[4*k], o[4*k+1], o[4*k+2], o[4*k+3]);
    }
    __syncthreads();

    // ---- fusedV: H-up + bias + LReLU + H-down in registers.
    // 512 units = (col-pair c 0..63, group q 0..7). Reads t1 rows 8q..8q+15 at cols 2c,2c+1.
    // Inner t = 0..11: ir rows s=2t (taps gA) and s=2t+1 (taps gB), global j = 16q + s - 4.
    // H-down: t2 row 8q+p accumulates ir s in [2p, 2p+9]  ->  pairs p <= t <= p+4.
    const int c = tid & 63;
    const int q = tid >> 6;                  // wave-uniform
    float accx[8] = {0.f,0.f,0.f,0.f,0.f,0.f,0.f,0.f};
    float accy[8] = {0.f,0.f,0.f,0.f,0.f,0.f,0.f,0.f};
    {
        v2f cc[16];
#pragma unroll
        for (int t = 0; t < 16; ++t)
            cc[t] = *(const v2f*)(s_t1 + (8 * q + t) * T1_STRIDE + 2 * c);
        const bool mlo = (q == 0);           // j = s-4 < 0     for t < 2
        const bool mhi = (q == 7);           // j = 108+s >= 128 for t >= 10
#pragma unroll
        for (int t = 0; t < 12; ++t) {
            float tax = fmaf(cc[t].x, gA[0], bv);
            float tay = fmaf(cc[t].y, gA[0], bv);
            float tbx = fmaf(cc[t].x, gB[0], bv);
            float tby = fmaf(cc[t].y, gB[0], bv);
#pragma unroll
            for (int k = 1; k < 5; ++k) {
                tax = fmaf(cc[t + k].x, gA[k], tax);
                tay = fmaf(cc[t + k].y, gA[k], tay);
                tbx = fmaf(cc[t + k].x, gB[k], tbx);
                tby = fmaf(cc[t + k].y, gB[k], tby);
            }
            if (mlo && t < 2)   { tax = 0.f; tay = 0.f; tbx = 0.f; tby = 0.f; }
            if (mhi && t >= 10) { tax = 0.f; tay = 0.f; tbx = 0.f; tby = 0.f; }
            // lrelu (unscaled): max(x, 0.2x)
            const float rax = fmaxf(tax, 0.2f * tax);
            const float ray = fmaxf(tay, 0.2f * tay);
            const float rbx = fmaxf(tbx, 0.2f * tbx);
            const float rby = fmaxf(tby, 0.2f * tby);
#pragma unroll
            for (int p = 0; p < 8; ++p) {
                if (p <= t && t <= p + 4) {
                    const int m = 4 - (t - p);
                    accx[p] = fmaf(rax, fhy[m], fmaf(rbx, fhx[m], accx[p]));
                    accy[p] = fmaf(ray, fhy[m], fmaf(rby, fhx[m], accy[p]));
                }
            }
        }
    }
    __syncthreads();   // all t1 reads done; t2 may overwrite the aliased LDS

    // ---- store acc -> t2 + halo cols
#pragma unroll
    for (int p = 0; p < 8; ++p)
        *(v2f*)(s_t2 + (8 * q + p) * T2_STRIDE + T2_OFF + 2 * c) = (v2f){accx[p], accy[p]};
    {
        const int rw = tid >> 3, cz = tid & 7;     // 64 rows x 8 halo words
        s_t2[rw * T2_STRIDE + (cz < 4 ? cz : 128 + cz)] = 0.f;
    }
    __syncthreads();

    // ---- Wdown: horizontal (W) /2 downsample -> global. 1024 units, 2 per thread.
#pragma unroll
    for (int s_ = 0; s_ < 2; ++s_) {
        const int u = tid + 512 * s_;
        const int oy = u >> 4, oxb = u & 15;
        const float* base = s_t2 + oy * T2_STRIDE + 8 * oxb;   // word T2_OFF + (8oxb-4)
        float wv[16];
#pragma unroll
        for (int t = 0; t < 4; ++t) {
            const float4 v = *(const float4*)(base + 4 * t);
            wv[4*t] = v.x; wv[4*t+1] = v.y; wv[4*t+2] = v.z; wv[4*t+3] = v.w;
        }
        float o2[4];
#pragma unroll
        for (int p = 0; p < 4; ++p) {
            float a2 = 0.f;
#pragma unroll
            for (int k = 0; k < 10; ++k)
                a2 = fmaf(wv[2*p + k], fd[10 - k], a2);
            o2[p] = a2;
        }
        float* po = out + (size_t)plane * (H * W) + oy * W + 4 * oxb;
        *(float4*)po = make_float4(o2[0], o2[1], o2[2], o2[3]);
    }
}

extern "C" void kernel_launch(void* const* d_in, const int* in_sizes, int n_in,
                              void* d_out, int out_size, void* d_ws, size_t ws_size,
                              hipStream_t stream) {
    const float* in  = (const float*)d_in[0];
    const float* bv  = (const float*)d_in[1];
    const float* upf = (const float*)d_in[2];
    const float* dnf = (const float*)d_in[3];
    float* out = (float*)d_out;
    const int planes = 8 * 512;
    afa_fused<<<planes, TPB, 0, stream>>>(in, bv, upf, dnf, out);
}